// Round 2
// baseline (10864.151 us; speedup 1.0000x reference)
//
#include <hip/hip_runtime.h>
#include <hip/hip_bf16.h>
#include <math.h>

typedef __hip_bfloat16 bf16;

constexpr int B_ = 8, N_ = 16384, ATTR_ = 14, G_ = 256, M_ = 32;
constexpr int BG = B_ * G_;       // 2048
constexpr int ROWS = BG * M_;     // 65536
constexpr int DIM_ = 384, HEADS_ = 6;

static inline int cdiv(int a, int b) { return (a + b - 1) / b; }

__device__ __forceinline__ float gelu_f(float x) {
  float x3 = x * x * x;
  float t = tanhf(0.7978845608028654f * (x + 0.044715f * x3));
  return 0.5f * x * (1.0f + t);
}

// ---------------- FPS: one block per batch, 1024 threads, 16 pts each ----------------
__global__ __launch_bounds__(1024) void fps_kernel(const float* __restrict__ xyz,
                                                   int* __restrict__ cidx) {
  const int b = blockIdx.x;
  const int tid = threadIdx.x;
  const float* base = xyz + (size_t)b * N_ * ATTR_;
  float px[16], py[16], pz[16], dist[16];
#pragma unroll
  for (int j = 0; j < 16; ++j) {
    int n = tid + j * 1024;
    px[j] = base[(size_t)n * ATTR_ + 0];
    py[j] = base[(size_t)n * ATTR_ + 1];
    pz[j] = base[(size_t)n * ATTR_ + 2];
    dist[j] = 1e10f;
  }
  __shared__ float s_v[16];
  __shared__ int s_i[16];
  __shared__ int s_far;
  int far = 0;
  for (int g = 0; g < G_; ++g) {
    if (tid == 0) cidx[b * G_ + g] = far;
    float cx = base[(size_t)far * ATTR_ + 0];
    float cy = base[(size_t)far * ATTR_ + 1];
    float cz = base[(size_t)far * ATTR_ + 2];
    float best = -1.0f; int bi = 0;
#pragma unroll
    for (int j = 0; j < 16; ++j) {
      float dx = __fsub_rn(px[j], cx);
      float dy = __fsub_rn(py[j], cy);
      float dz = __fsub_rn(pz[j], cz);
      float d = __fadd_rn(__fadd_rn(__fmul_rn(dx, dx), __fmul_rn(dy, dy)), __fmul_rn(dz, dz));
      float nd = fminf(dist[j], d);
      dist[j] = nd;
      int n = tid + j * 1024;
      if (nd > best) { best = nd; bi = n; }  // ascending n -> first-index kept
    }
    for (int off = 32; off > 0; off >>= 1) {
      float ov = __shfl_down(best, off);
      int   oi = __shfl_down(bi, off);
      if (ov > best || (ov == best && oi < bi)) { best = ov; bi = oi; }
    }
    if ((tid & 63) == 0) { s_v[tid >> 6] = best; s_i[tid >> 6] = bi; }
    __syncthreads();
    if (tid == 0) {
      float bv = s_v[0]; int bj = s_i[0];
      for (int w = 1; w < 16; ++w)
        if (s_v[w] > bv || (s_v[w] == bv && s_i[w] < bj)) { bv = s_v[w]; bj = s_i[w]; }
      s_far = bj;
    }
    __syncthreads();
    far = s_far;
  }
}

// ---------------- per-point squared norm over 14 attrs ----------------
__global__ void pn2_kernel(const float* __restrict__ xyz, float* __restrict__ pn2) {
  int gid = blockIdx.x * blockDim.x + threadIdx.x;
  if (gid >= B_ * N_) return;
  const float* p = xyz + (size_t)gid * ATTR_;
  float s = 0.f;
#pragma unroll
  for (int a = 0; a < ATTR_; ++a) s = __fadd_rn(s, __fmul_rn(p[a], p[a]));
  pn2[gid] = s;
}

// ---------------- KNN: one block per (b,g); iterative argmin over LDS d2 ----------------
__global__ __launch_bounds__(256) void knn_kernel(const float* __restrict__ xyz,
                                                  const float* __restrict__ pn2,
                                                  const int* __restrict__ cidx,
                                                  int* __restrict__ knn) {
  const int bg = blockIdx.x;
  const int b = bg >> 8;
  const int tid = threadIdx.x;
  __shared__ float d2s[N_];
  __shared__ float catt[ATTR_];
  __shared__ float lv[256]; __shared__ int li[256];
  __shared__ float rv[256]; __shared__ int ri[256];
  const float* xb = xyz + (size_t)b * N_ * ATTR_;
  if (tid == 0) {
    int ci = cidx[bg];
    for (int a = 0; a < ATTR_; ++a) catt[a] = xb[(size_t)ci * ATTR_ + a];
  }
  __syncthreads();
  float cn2 = 0.f;
#pragma unroll
  for (int a = 0; a < ATTR_; ++a) cn2 = __fadd_rn(cn2, __fmul_rn(catt[a], catt[a]));
  const float* pnb = pn2 + (size_t)b * N_;
  const int base = tid * 64;
  float bv = 3.0e38f; int bi = 0;
  for (int j = 0; j < 64; ++j) {
    int n = base + j;
    const float* p = xb + (size_t)n * ATTR_;
    float dot = 0.f;
#pragma unroll
    for (int a = 0; a < ATTR_; ++a) dot = __fadd_rn(dot, __fmul_rn(catt[a], p[a]));
    float v = __fsub_rn(__fadd_rn(cn2, pnb[n]), __fmul_rn(2.0f, dot));
    d2s[n] = v;
    if (v < bv) { bv = v; bi = n; }
  }
  lv[tid] = bv; li[tid] = bi;
  __syncthreads();
  for (int m = 0; m < M_; ++m) {
    rv[tid] = lv[tid]; ri[tid] = li[tid];
    __syncthreads();
    for (int s = 128; s > 0; s >>= 1) {
      if (tid < s) {
        float ov = rv[tid + s]; int oi = ri[tid + s];
        if (ov < rv[tid] || (ov == rv[tid] && oi < ri[tid])) { rv[tid] = ov; ri[tid] = oi; }
      }
      __syncthreads();
    }
    int win = ri[0];
    if (tid == 0) knn[(size_t)bg * M_ + m] = win;
    if (tid == (win >> 6)) {
      d2s[win] = 3.0e38f;
      float nbv = 3.0e38f; int nbi = 0;
      for (int j = 0; j < 64; ++j) {
        int n = base + j;
        float v = d2s[n];
        if (v < nbv) { nbv = v; nbi = n; }
      }
      lv[tid] = nbv; li[tid] = nbi;
    }
    __syncthreads();
  }
}

// ---------------- gather neighbors, center first 3 coords, emit centers ----------------
__global__ void pg_build_kernel(const float* __restrict__ xyz, const int* __restrict__ cidx,
                                const int* __restrict__ knn, float* __restrict__ pg,
                                float* __restrict__ center) {
  int gid = blockIdx.x * blockDim.x + threadIdx.x;
  if (gid >= ROWS) return;
  int bg = gid >> 5, mm = gid & 31;
  int b = bg >> 8;
  int ci = cidx[bg];
  int ni = knn[(size_t)bg * M_ + mm];
  const float* c = xyz + ((size_t)b * N_ + ci) * ATTR_;
  const float* p = xyz + ((size_t)b * N_ + ni) * ATTR_;
  float* o = pg + (size_t)gid * ATTR_;
#pragma unroll
  for (int a = 0; a < 3; ++a) o[a] = __fsub_rn(p[a], c[a]);
#pragma unroll
  for (int a = 3; a < ATTR_; ++a) o[a] = p[a];
  if (mm == 0) {
    center[bg * 3 + 0] = c[0]; center[bg * 3 + 1] = c[1]; center[bg * 3 + 2] = c[2];
  }
}

// ---------------- generic tiled GEMM: C = epi( pro(A) @ W^T ) ----------------
// A: [Mrows x K] (lda), W: [OC x K], C: [Mrows x OC]
template<bool ABF, bool PRO, bool BIAS, bool GELUE, bool RES, bool EYE, bool OBF>
__global__ __launch_bounds__(256) void gemm_kernel(
    const void* __restrict__ Ap, const float* __restrict__ W,
    const float* __restrict__ bias, const float* __restrict__ pss,
    const float* __restrict__ res, void* __restrict__ Cp,
    int Mrows, int K, int OC, int lda) {
  __shared__ float As[16][68];
  __shared__ float Ws[16][68];
  const int tid = threadIdx.x;
  const int tx = tid & 15, ty = tid >> 4;
  const int row0 = blockIdx.y * 64, col0 = blockIdx.x * 64;
  float acc[4][4] = {{0.f}};
  const float* Af = (const float*)Ap;
  const bf16* Ab = (const bf16*)Ap;
  const int r = tid >> 2;
  const int kb = (tid & 3) * 4;
  for (int k0 = 0; k0 < K; k0 += 16) {
#pragma unroll
    for (int i = 0; i < 4; ++i) {
      int kk = kb + i, kg = k0 + kk;
      float a = 0.f, w = 0.f;
      if (kg < K) {
        size_t ai = (size_t)(row0 + r) * lda + kg;
        a = ABF ? __bfloat162float(Ab[ai]) : Af[ai];
        if (PRO) a = fmaxf(0.f, fmaf(a, pss[kg], pss[K + kg]));
        int oc = col0 + r;
        if (oc < OC) w = W[(size_t)oc * K + kg];
      }
      As[kk][r] = a;
      Ws[kk][r] = w;
    }
    __syncthreads();
#pragma unroll
    for (int kk = 0; kk < 16; ++kk) {
      float av[4], bv[4];
#pragma unroll
      for (int i = 0; i < 4; ++i) av[i] = As[kk][ty * 4 + i];
#pragma unroll
      for (int j = 0; j < 4; ++j) bv[j] = Ws[kk][tx * 4 + j];
#pragma unroll
      for (int i = 0; i < 4; ++i)
#pragma unroll
        for (int j = 0; j < 4; ++j) acc[i][j] = fmaf(av[i], bv[j], acc[i][j]);
    }
    __syncthreads();
  }
#pragma unroll
  for (int i = 0; i < 4; ++i) {
    int row = row0 + ty * 4 + i;
#pragma unroll
    for (int j = 0; j < 4; ++j) {
      int c = col0 + tx * 4 + j;
      if (c >= OC) continue;
      float v = acc[i][j];
      if (BIAS) v += bias[c];
      if (EYE) { if ((c / 6) == (c % 6)) v += 1.0f; }
      if (GELUE) v = gelu_f(v);
      if (RES) v += res[(size_t)row * OC + c];
      size_t oi = (size_t)row * OC + c;
      if (OBF) ((bf16*)Cp)[oi] = __float2bfloat16(v);
      else ((float*)Cp)[oi] = v;
    }
  }
}

// ---------------- BatchNorm stats (sum / sumsq per channel) ----------------
__global__ __launch_bounds__(256) void bn_stats_kernel(const bf16* __restrict__ Y,
                                                       float* __restrict__ stats, int C) {
  const int r0 = blockIdx.x * 256;
  const int tid = threadIdx.x;
  for (int c = tid; c < C; c += 256) {
    float s = 0.f, q = 0.f;
    for (int r = 0; r < 256; ++r) {
      float y = __bfloat162float(Y[(size_t)(r0 + r) * C + c]);
      s += y; q += y * y;
    }
    atomicAdd(&stats[c], s);
    atomicAdd(&stats[C + c], q);
  }
}

__global__ void bn_fin_kernel(const float* __restrict__ stats, const float* __restrict__ g,
                              const float* __restrict__ b, float* __restrict__ ss, int C) {
  int c = blockIdx.x * blockDim.x + threadIdx.x;
  if (c >= C) return;
  const float inv_n = 1.0f / (float)ROWS;
  float m = stats[c] * inv_n;
  float v = stats[C + c] * inv_n - m * m;
  float sc = g[c] * (1.0f / sqrtf(v + 1e-5f));
  ss[c] = sc;
  ss[C + c] = b[c] - m * sc;
}

// ---------------- max over the M=32 neighbor axis, with BN(+ReLU) applied ----------------
template<bool RELU>
__global__ void maxpool_kernel(const bf16* __restrict__ Y, const float* __restrict__ ss,
                               float* __restrict__ out, int C) {
  int gid = blockIdx.x * blockDim.x + threadIdx.x;
  if (gid >= BG * C) return;
  int bg = gid / C, c = gid - bg * C;
  float sc = ss[c], sh = ss[C + c];
  float m = -3.0e38f;
  for (int j = 0; j < M_; ++j) {
    float y = __bfloat162float(Y[((size_t)bg * M_ + j) * C + c]);
    float v = fmaf(y, sc, sh);
    if (RELU) v = fmaxf(v, 0.f);
    m = fmaxf(m, v);
  }
  out[gid] = m;
}

// ---------------- apply per-group 6x6 TNet transform ----------------
__global__ void tnet_apply_kernel(const float* __restrict__ pg, const float* __restrict__ tmat,
                                  float* __restrict__ pg2) {
  int row = blockIdx.x * blockDim.x + threadIdx.x;
  if (row >= ROWS) return;
  int bg = row >> 5;
  const float* t = tmat + (size_t)bg * 36;
  const float* in = pg + (size_t)row * ATTR_;
  float* o = pg2 + (size_t)row * ATTR_;
  float x[6];
#pragma unroll
  for (int c = 0; c < 6; ++c) x[c] = in[c];
#pragma unroll
  for (int k = 0; k < 6; ++k) {
    float s = 0.f;
#pragma unroll
    for (int c = 0; c < 6; ++c) s = fmaf(x[c], t[c * 6 + k], s);
    o[k] = s;
  }
#pragma unroll
  for (int a = 6; a < ATTR_; ++a) o[a] = in[a];
}

// ---------------- LayerNorm (optionally x+pos first, writing h_in) ----------------
template<bool ADDPOS>
__global__ __launch_bounds__(128) void ln_kernel(const float* __restrict__ x,
                                                 const float* __restrict__ pos,
                                                 const float* __restrict__ g,
                                                 const float* __restrict__ b,
                                                 float* __restrict__ hin,
                                                 float* __restrict__ y) {
  const int row = blockIdx.x;
  const int tid = threadIdx.x;
  float v[3];
  float s = 0.f;
#pragma unroll
  for (int i = 0; i < 3; ++i) {
    int c = tid + i * 128;
    float t = x[(size_t)row * DIM_ + c];
    if (ADDPOS) t += pos[(size_t)row * DIM_ + c];
    v[i] = t; s += t;
  }
  for (int off = 32; off > 0; off >>= 1) s += __shfl_down(s, off);
  __shared__ float sa[2], sb[2];
  if ((tid & 63) == 0) sa[tid >> 6] = s;
  __syncthreads();
  float mean = (sa[0] + sa[1]) * (1.0f / DIM_);
  float q = 0.f;
#pragma unroll
  for (int i = 0; i < 3; ++i) { float d = v[i] - mean; q += d * d; }
  for (int off = 32; off > 0; off >>= 1) q += __shfl_down(q, off);
  if ((tid & 63) == 0) sb[tid >> 6] = q;
  __syncthreads();
  float var = (sb[0] + sb[1]) * (1.0f / DIM_);
  float rs = 1.0f / sqrtf(var + 1e-5f);
#pragma unroll
  for (int i = 0; i < 3; ++i) {
    int c = tid + i * 128;
    if (ADDPOS) hin[(size_t)row * DIM_ + c] = v[i];
    y[(size_t)row * DIM_ + c] = fmaf((v[i] - mean) * rs, g[c], b[c]);
  }
}

// ---------------- attention: one block per (b, h, 64-query tile) ----------------
__global__ __launch_bounds__(256) void attn_kernel(const float* __restrict__ qkv,
                                                   float* __restrict__ obuf) {
  const int blk = blockIdx.x;
  const int qt = blk & 3;
  const int bh = blk >> 2;
  const int b = bh / HEADS_, h = bh % HEADS_;
  const int tid = threadIdx.x;
  __shared__ float Qs[64][65];
  __shared__ float KVs[256][65];
  __shared__ float Ss[64][257];
  const int n0 = qt * 64;
  const size_t qbase = (size_t)b * G_ * (3 * DIM_);
#pragma unroll 4
  for (int i = 0; i < 16; ++i) {
    int idx = i * 256 + tid;
    int qr = idx >> 6, d = idx & 63;
    Qs[qr][d] = qkv[qbase + (size_t)(n0 + qr) * (3 * DIM_) + h * 64 + d];
  }
#pragma unroll 4
  for (int i = 0; i < 64; ++i) {
    int idx = i * 256 + tid;
    int kr = idx >> 6, d = idx & 63;
    KVs[kr][d] = qkv[qbase + (size_t)kr * (3 * DIM_) + DIM_ + h * 64 + d];
  }
  __syncthreads();
  const int q = tid >> 2, kl = tid & 3;
  float lmax = -3.0e38f;
#pragma unroll 4
  for (int kk = 0; kk < 64; ++kk) {
    int k = kl + kk * 4;
    float s = 0.f;
#pragma unroll
    for (int d = 0; d < 64; ++d) s = fmaf(Qs[q][d], KVs[k][d], s);
    s *= 0.125f;
    Ss[q][k] = s;
    lmax = fmaxf(lmax, s);
  }
  lmax = fmaxf(lmax, __shfl_xor(lmax, 1));
  lmax = fmaxf(lmax, __shfl_xor(lmax, 2));
  float lsum = 0.f;
#pragma unroll 4
  for (int kk = 0; kk < 64; ++kk) {
    int k = kl + kk * 4;
    float e = expf(Ss[q][k] - lmax);
    Ss[q][k] = e;
    lsum += e;
  }
  lsum += __shfl_xor(lsum, 1);
  lsum += __shfl_xor(lsum, 2);
#pragma unroll 4
  for (int kk = 0; kk < 64; ++kk) {
    int k = kl + kk * 4;
    Ss[q][k] = Ss[q][k] / lsum;
  }
  __syncthreads();
#pragma unroll 4
  for (int i = 0; i < 64; ++i) {
    int idx = i * 256 + tid;
    int kr = idx >> 6, d = idx & 63;
    KVs[kr][d] = qkv[qbase + (size_t)kr * (3 * DIM_) + 2 * DIM_ + h * 64 + d];
  }
  __syncthreads();
  float oacc[16];
#pragma unroll
  for (int i = 0; i < 16; ++i) oacc[i] = 0.f;
  for (int k = 0; k < 256; ++k) {
    float s = Ss[q][k];
#pragma unroll
    for (int dd = 0; dd < 16; ++dd) oacc[dd] = fmaf(s, KVs[k][kl + dd * 4], oacc[dd]);
  }
  float* ob = obuf + (size_t)(b * G_ + n0 + q) * DIM_ + h * 64;
#pragma unroll
  for (int dd = 0; dd < 16; ++dd) ob[kl + dd * 4] = oacc[dd];
}

// =======================================================================================
extern "C" void kernel_launch(void* const* d_in, const int* in_sizes, int n_in,
                              void* d_out, int out_size, void* d_ws, size_t ws_size,
                              hipStream_t stream) {
  const float* xyz      = (const float*)d_in[0];
  const float* tn_c1_w  = (const float*)d_in[1];
  const float* tn_c1_b  = (const float*)d_in[2];
  const float* tn_bn1_g = (const float*)d_in[3];
  const float* tn_bn1_b = (const float*)d_in[4];
  const float* tn_c2_w  = (const float*)d_in[5];
  const float* tn_c2_b  = (const float*)d_in[6];
  const float* tn_bn2_g = (const float*)d_in[7];
  const float* tn_bn2_b = (const float*)d_in[8];
  const float* tn_fc_w  = (const float*)d_in[9];
  const float* tn_fc_b  = (const float*)d_in[10];
  const float* e_c1_w = (const float*)d_in[11];
  const float* e_c1_b = (const float*)d_in[12];
  const float* e_bn1_g = (const float*)d_in[13];
  const float* e_bn1_b = (const float*)d_in[14];
  const float* e_c2_w = (const float*)d_in[15];
  const float* e_c2_b = (const float*)d_in[16];
  const float* e_bn2_g = (const float*)d_in[17];
  const float* e_bn2_b = (const float*)d_in[18];
  const float* e_c3_w = (const float*)d_in[19];
  const float* e_c3_b = (const float*)d_in[20];
  const float* e_bn3_g = (const float*)d_in[21];
  const float* e_bn3_b = (const float*)d_in[22];
  const float* e_c4_w = (const float*)d_in[23];
  const float* e_c4_b = (const float*)d_in[24];
  const float* e_bn4_g = (const float*)d_in[25];
  const float* e_bn4_b = (const float*)d_in[26];
  const float* reduce_w = (const float*)d_in[27];
  const float* reduce_b = (const float*)d_in[28];
  const float* pos1_w = (const float*)d_in[29];
  const float* pos1_b = (const float*)d_in[30];
  const float* pos2_w = (const float*)d_in[31];
  const float* pos2_b = (const float*)d_in[32];
  const float* ln1_g = (const float*)d_in[33];
  const float* ln1_b = (const float*)d_in[34];
  const float* qkv_w = (const float*)d_in[35];
  const float* proj_w = (const float*)d_in[36];
  const float* proj_b = (const float*)d_in[37];
  const float* ln2_g = (const float*)d_in[38];
  const float* ln2_b = (const float*)d_in[39];
  const float* fc1_w = (const float*)d_in[40];
  const float* fc1_b = (const float*)d_in[41];
  const float* fc2_w = (const float*)d_in[42];
  const float* fc2_b = (const float*)d_in[43];
  (void)in_sizes; (void)n_in; (void)out_size; (void)ws_size;

  char* ws = (char*)d_ws;
  size_t off = 0;
  auto alloc = [&](size_t bytes) -> void* {
    void* p = ws + off;
    off = (off + bytes + 255) & ~(size_t)255;
    return p;
  };

  char* stats_begin = ws + off;
  float* stats_tn1 = (float*)alloc(2 * 64 * 4);
  float* stats_tn2 = (float*)alloc(2 * 512 * 4);
  float* stats_e1 = (float*)alloc(2 * 128 * 4);
  float* stats_e2 = (float*)alloc(2 * 256 * 4);
  float* stats_e3 = (float*)alloc(2 * 512 * 4);
  float* stats_e4 = (float*)alloc(2 * 1024 * 4);
  size_t stats_len = (size_t)((ws + off) - stats_begin);
  float* ss_tn1 = (float*)alloc(2 * 64 * 4);
  float* ss_tn2 = (float*)alloc(2 * 512 * 4);
  float* ss_e1 = (float*)alloc(2 * 128 * 4);
  float* ss_e2 = (float*)alloc(2 * 256 * 4);
  float* ss_e3 = (float*)alloc(2 * 512 * 4);
  float* ss_e4 = (float*)alloc(2 * 1024 * 4);
  int* cidx = (int*)alloc((size_t)BG * 4);
  int* knn = (int*)alloc((size_t)ROWS * 4);
  float* pn2 = (float*)alloc((size_t)B_ * N_ * 4);
  float* center = (float*)alloc((size_t)BG * 3 * 4);
  float* pg = (float*)alloc((size_t)ROWS * ATTR_ * 4);
  float* pg2 = (float*)alloc((size_t)ROWS * ATTR_ * 4);
  float* hmax = (float*)alloc((size_t)BG * 512 * 4);
  float* tmat = (float*)alloc((size_t)BG * 36 * 4);
  float* tokens = (float*)alloc((size_t)BG * 1024 * 4);
  float* xb = (float*)alloc((size_t)BG * DIM_ * 4);
  float* posb = (float*)alloc((size_t)BG * DIM_ * 4);
  float* hinb = (float*)alloc((size_t)BG * DIM_ * 4);
  float* yb = (float*)alloc((size_t)BG * DIM_ * 4);
  float* qkvb = (float*)alloc((size_t)BG * 3 * DIM_ * 4);
  float* obf = (float*)alloc((size_t)BG * DIM_ * 4);
  float* hmlp = (float*)alloc((size_t)BG * 1536 * 4);
  float* p1 = (float*)alloc((size_t)BG * 128 * 4);
  bf16* Bbuf0 = (bf16*)alloc((size_t)ROWS * 512 * 2);   // 64 MB
  bf16* Bbuf1 = (bf16*)alloc((size_t)ROWS * 1024 * 2);  // 128 MB

  hipMemsetAsync(stats_begin, 0, stats_len, stream);

  fps_kernel<<<B_, 1024, 0, stream>>>(xyz, cidx);
  pn2_kernel<<<cdiv(B_ * N_, 256), 256, 0, stream>>>(xyz, pn2);
  knn_kernel<<<BG, 256, 0, stream>>>(xyz, pn2, cidx, knn);
  pg_build_kernel<<<cdiv(ROWS, 256), 256, 0, stream>>>(xyz, cidx, knn, pg, center);

  // ---- TNet ----
  gemm_kernel<false, false, true, false, false, false, true>
      <<<dim3(1, ROWS / 64), 256, 0, stream>>>(pg, tn_c1_w, tn_c1_b, nullptr, nullptr,
                                               Bbuf0, ROWS, 6, 64, ATTR_);
  bn_stats_kernel<<<ROWS / 256, 256, 0, stream>>>(Bbuf0, stats_tn1, 64);
  bn_fin_kernel<<<1, 64, 0, stream>>>(stats_tn1, tn_bn1_g, tn_bn1_b, ss_tn1, 64);
  gemm_kernel<true, true, true, false, false, false, true>
      <<<dim3(8, ROWS / 64), 256, 0, stream>>>(Bbuf0, tn_c2_w, tn_c2_b, ss_tn1, nullptr,
                                               Bbuf1, ROWS, 64, 512, 64);
  bn_stats_kernel<<<ROWS / 256, 256, 0, stream>>>(Bbuf1, stats_tn2, 512);
  bn_fin_kernel<<<2, 256, 0, stream>>>(stats_tn2, tn_bn2_g, tn_bn2_b, ss_tn2, 512);
  maxpool_kernel<true><<<cdiv(BG * 512, 256), 256, 0, stream>>>(Bbuf1, ss_tn2, hmax, 512);
  gemm_kernel<false, false, true, false, false, true, false>
      <<<dim3(1, BG / 64), 256, 0, stream>>>(hmax, tn_fc_w, tn_fc_b, nullptr, nullptr,
                                             tmat, BG, 512, 36, 512);
  tnet_apply_kernel<<<cdiv(ROWS, 256), 256, 0, stream>>>(pg, tmat, pg2);

  // ---- Encoder ----
  gemm_kernel<false, false, true, false, false, false, true>
      <<<dim3(2, ROWS / 64), 256, 0, stream>>>(pg2, e_c1_w, e_c1_b, nullptr, nullptr,
                                               Bbuf0, ROWS, ATTR_, 128, ATTR_);
  bn_stats_kernel<<<ROWS / 256, 256, 0, stream>>>(Bbuf0, stats_e1, 128);
  bn_fin_kernel<<<1, 128, 0, stream>>>(stats_e1, e_bn1_g, e_bn1_b, ss_e1, 128);
  gemm_kernel<true, true, true, false, false, false, true>
      <<<dim3(4, ROWS / 64), 256, 0, stream>>>(Bbuf0, e_c2_w, e_c2_b, ss_e1, nullptr,
                                               Bbuf1, ROWS, 128, 256, 128);
  bn_stats_kernel<<<ROWS / 256, 256, 0, stream>>>(Bbuf1, stats_e2, 256);
  bn_fin_kernel<<<1, 256, 0, stream>>>(stats_e2, e_bn2_g, e_bn2_b, ss_e2, 256);
  gemm_kernel<true, true, true, false, false, false, true>
      <<<dim3(8, ROWS / 64), 256, 0, stream>>>(Bbuf1, e_c3_w, e_c3_b, ss_e2, nullptr,
                                               Bbuf0, ROWS, 256, 512, 256);
  bn_stats_kernel<<<ROWS / 256, 256, 0, stream>>>(Bbuf0, stats_e3, 512);
  bn_fin_kernel<<<2, 256, 0, stream>>>(stats_e3, e_bn3_g, e_bn3_b, ss_e3, 512);
  gemm_kernel<true, true, true, false, false, false, true>
      <<<dim3(16, ROWS / 64), 256, 0, stream>>>(Bbuf0, e_c4_w, e_c4_b, ss_e3, nullptr,
                                                Bbuf1, ROWS, 512, 1024, 512);
  bn_stats_kernel<<<ROWS / 256, 256, 0, stream>>>(Bbuf1, stats_e4, 1024);
  bn_fin_kernel<<<4, 256, 0, stream>>>(stats_e4, e_bn4_g, e_bn4_b, ss_e4, 1024);
  maxpool_kernel<false><<<cdiv(BG * 1024, 256), 256, 0, stream>>>(Bbuf1, ss_e4, tokens, 1024);

  // ---- reduce + pos ----
  gemm_kernel<false, false, true, false, false, false, false>
      <<<dim3(6, BG / 64), 256, 0, stream>>>(tokens, reduce_w, reduce_b, nullptr, nullptr,
                                             xb, BG, 1024, DIM_, 1024);
  gemm_kernel<false, false, true, true, false, false, false>
      <<<dim3(2, BG / 64), 256, 0, stream>>>(center, pos1_w, pos1_b, nullptr, nullptr,
                                             p1, BG, 3, 128, 3);
  gemm_kernel<false, false, true, false, false, false, false>
      <<<dim3(6, BG / 64), 256, 0, stream>>>(p1, pos2_w, pos2_b, nullptr, nullptr,
                                             posb, BG, 128, DIM_, 128);

  // ---- transformer ----
  int slot = 0;
  for (int i = 0; i < 12; ++i) {
    ln_kernel<true><<<BG, 128, 0, stream>>>(xb, posb, ln1_g + (size_t)i * DIM_,
                                            ln1_b + (size_t)i * DIM_, hinb, yb);
    gemm_kernel<false, false, false, false, false, false, false>
        <<<dim3(18, BG / 64), 256, 0, stream>>>(yb, qkv_w + (size_t)i * 3 * DIM_ * DIM_,
                                                nullptr, nullptr, nullptr, qkvb,
                                                BG, DIM_, 3 * DIM_, DIM_);
    attn_kernel<<<B_ * HEADS_ * 4, 256, 0, stream>>>(qkvb, obf);
    gemm_kernel<false, false, true, false, true, false, false>
        <<<dim3(6, BG / 64), 256, 0, stream>>>(obf, proj_w + (size_t)i * DIM_ * DIM_,
                                               proj_b + (size_t)i * DIM_, nullptr, hinb,
                                               xb, BG, DIM_, DIM_, DIM_);
    ln_kernel<false><<<BG, 128, 0, stream>>>(xb, nullptr, ln2_g + (size_t)i * DIM_,
                                             ln2_b + (size_t)i * DIM_, nullptr, yb);
    gemm_kernel<false, false, true, true, false, false, false>
        <<<dim3(24, BG / 64), 256, 0, stream>>>(yb, fc1_w + (size_t)i * 1536 * DIM_,
                                                fc1_b + (size_t)i * 1536, nullptr, nullptr,
                                                hmlp, BG, DIM_, 1536, DIM_);
    gemm_kernel<false, false, true, false, true, false, false>
        <<<dim3(6, BG / 64), 256, 0, stream>>>(hmlp, fc2_w + (size_t)i * DIM_ * 1536,
                                               fc2_b + (size_t)i * DIM_, nullptr, xb,
                                               xb, BG, 1536, DIM_, 1536);
    if (i == 3 || i == 7 || i == 11) {
      hipMemcpyAsync((float*)d_out + (size_t)slot * BG * DIM_, xb,
                     (size_t)BG * DIM_ * 4, hipMemcpyDeviceToDevice, stream);
      ++slot;
    }
  }
}

// Round 3
// 4766.420 us; speedup vs baseline: 2.2793x; 2.2793x over previous
//
#include <hip/hip_runtime.h>
#include <hip/hip_bf16.h>
#include <math.h>

typedef __hip_bfloat16 bf16;
typedef __attribute__((ext_vector_type(8))) short bfrag;   // 8 bf16 (4 VGPR)
typedef __attribute__((ext_vector_type(4))) float f32x4;

constexpr int B_ = 8, N_ = 16384, ATTR_ = 14, G_ = 256, M_ = 32;
constexpr int BG = B_ * G_;       // 2048
constexpr int ROWS = BG * M_;     // 65536
constexpr int DIM_ = 384, HEADS_ = 6;

static inline int cdiv(int a, int b) { return (a + b - 1) / b; }

__device__ __forceinline__ float gelu_f(float x) {
  float x3 = x * x * x;
  float t = tanhf(0.7978845608028654f * (x + 0.044715f * x3));
  return 0.5f * x * (1.0f + t);
}

// ---------------- FPS: one block per batch, 1024 threads, 16 pts each ----------------
__global__ __launch_bounds__(1024) void fps_kernel(const float* __restrict__ xyz,
                                                   int* __restrict__ cidx) {
  const int b = blockIdx.x;
  const int tid = threadIdx.x;
  const float* base = xyz + (size_t)b * N_ * ATTR_;
  float px[16], py[16], pz[16], dist[16];
#pragma unroll
  for (int j = 0; j < 16; ++j) {
    int n = tid + j * 1024;
    px[j] = base[(size_t)n * ATTR_ + 0];
    py[j] = base[(size_t)n * ATTR_ + 1];
    pz[j] = base[(size_t)n * ATTR_ + 2];
    dist[j] = 1e10f;
  }
  __shared__ float s_v[16];
  __shared__ int s_i[16];
  __shared__ int s_far;
  int far = 0;
  for (int g = 0; g < G_; ++g) {
    if (tid == 0) cidx[b * G_ + g] = far;
    float cx = base[(size_t)far * ATTR_ + 0];
    float cy = base[(size_t)far * ATTR_ + 1];
    float cz = base[(size_t)far * ATTR_ + 2];
    float best = -1.0f; int bi = 0;
#pragma unroll
    for (int j = 0; j < 16; ++j) {
      float dx = __fsub_rn(px[j], cx);
      float dy = __fsub_rn(py[j], cy);
      float dz = __fsub_rn(pz[j], cz);
      float d = __fadd_rn(__fadd_rn(__fmul_rn(dx, dx), __fmul_rn(dy, dy)), __fmul_rn(dz, dz));
      float nd = fminf(dist[j], d);
      dist[j] = nd;
      int n = tid + j * 1024;
      if (nd > best) { best = nd; bi = n; }
    }
    for (int off = 32; off > 0; off >>= 1) {
      float ov = __shfl_down(best, off);
      int   oi = __shfl_down(bi, off);
      if (ov > best || (ov == best && oi < bi)) { best = ov; bi = oi; }
    }
    if ((tid & 63) == 0) { s_v[tid >> 6] = best; s_i[tid >> 6] = bi; }
    __syncthreads();
    if (tid == 0) {
      float bv = s_v[0]; int bj = s_i[0];
      for (int w = 1; w < 16; ++w)
        if (s_v[w] > bv || (s_v[w] == bv && s_i[w] < bj)) { bv = s_v[w]; bj = s_i[w]; }
      s_far = bj;
    }
    __syncthreads();
    far = s_far;
  }
}

// ---------------- per-point squared norm over 14 attrs ----------------
__global__ void pn2_kernel(const float* __restrict__ xyz, float* __restrict__ pn2) {
  int gid = blockIdx.x * blockDim.x + threadIdx.x;
  if (gid >= B_ * N_) return;
  const float* p = xyz + (size_t)gid * ATTR_;
  float s = 0.f;
#pragma unroll
  for (int a = 0; a < ATTR_; ++a) s = __fadd_rn(s, __fmul_rn(p[a], p[a]));
  pn2[gid] = s;
}

// ---------------- KNN: one block per (b,g); iterative argmin over LDS d2 ----------------
__global__ __launch_bounds__(256) void knn_kernel(const float* __restrict__ xyz,
                                                  const float* __restrict__ pn2,
                                                  const int* __restrict__ cidx,
                                                  int* __restrict__ knn) {
  const int bg = blockIdx.x;
  const int b = bg >> 8;
  const int tid = threadIdx.x;
  __shared__ float d2s[N_];
  __shared__ float catt[ATTR_];
  __shared__ float lv[256]; __shared__ int li[256];
  __shared__ float rv[256]; __shared__ int ri[256];
  const float* xb = xyz + (size_t)b * N_ * ATTR_;
  if (tid == 0) {
    int ci = cidx[bg];
    for (int a = 0; a < ATTR_; ++a) catt[a] = xb[(size_t)ci * ATTR_ + a];
  }
  __syncthreads();
  float cn2 = 0.f;
#pragma unroll
  for (int a = 0; a < ATTR_; ++a) cn2 = __fadd_rn(cn2, __fmul_rn(catt[a], catt[a]));
  const float* pnb = pn2 + (size_t)b * N_;
  const int base = tid * 64;
  float bv = 3.0e38f; int bi = 0;
  for (int j = 0; j < 64; ++j) {
    int n = base + j;
    const float* p = xb + (size_t)n * ATTR_;
    float dot = 0.f;
#pragma unroll
    for (int a = 0; a < ATTR_; ++a) dot = __fadd_rn(dot, __fmul_rn(catt[a], p[a]));
    float v = __fsub_rn(__fadd_rn(cn2, pnb[n]), __fmul_rn(2.0f, dot));
    d2s[n] = v;
    if (v < bv) { bv = v; bi = n; }
  }
  lv[tid] = bv; li[tid] = bi;
  __syncthreads();
  for (int m = 0; m < M_; ++m) {
    rv[tid] = lv[tid]; ri[tid] = li[tid];
    __syncthreads();
    for (int s = 128; s > 0; s >>= 1) {
      if (tid < s) {
        float ov = rv[tid + s]; int oi = ri[tid + s];
        if (ov < rv[tid] || (ov == rv[tid] && oi < ri[tid])) { rv[tid] = ov; ri[tid] = oi; }
      }
      __syncthreads();
    }
    int win = ri[0];
    if (tid == 0) knn[(size_t)bg * M_ + m] = win;
    if (tid == (win >> 6)) {
      d2s[win] = 3.0e38f;
      float nbv = 3.0e38f; int nbi = 0;
      for (int j = 0; j < 64; ++j) {
        int n = base + j;
        float v = d2s[n];
        if (v < nbv) { nbv = v; nbi = n; }
      }
      lv[tid] = nbv; li[tid] = nbi;
    }
    __syncthreads();
  }
}

// ---------------- gather neighbors, center first 3 coords, emit centers ----------------
__global__ void pg_build_kernel(const float* __restrict__ xyz, const int* __restrict__ cidx,
                                const int* __restrict__ knn, float* __restrict__ pg,
                                float* __restrict__ center) {
  int gid = blockIdx.x * blockDim.x + threadIdx.x;
  if (gid >= ROWS) return;
  int bg = gid >> 5, mm = gid & 31;
  int b = bg >> 8;
  int ci = cidx[bg];
  int ni = knn[(size_t)bg * M_ + mm];
  const float* c = xyz + ((size_t)b * N_ + ci) * ATTR_;
  const float* p = xyz + ((size_t)b * N_ + ni) * ATTR_;
  float* o = pg + (size_t)gid * ATTR_;
#pragma unroll
  for (int a = 0; a < 3; ++a) o[a] = __fsub_rn(p[a], c[a]);
#pragma unroll
  for (int a = 3; a < ATTR_; ++a) o[a] = p[a];
  if (mm == 0) {
    center[bg * 3 + 0] = c[0]; center[bg * 3 + 1] = c[1]; center[bg * 3 + 2] = c[2];
  }
}

// ---------------- SIMT GEMM (small-K / odd shapes only) ----------------
template<bool ABF, bool BIAS, bool GELUE, bool EYE, bool OBF>
__global__ __launch_bounds__(256) void gemm_kernel(
    const void* __restrict__ Ap, const float* __restrict__ W,
    const float* __restrict__ bias, void* __restrict__ Cp,
    int Mrows, int K, int OC, int lda) {
  __shared__ float As[16][68];
  __shared__ float Ws[16][68];
  const int tid = threadIdx.x;
  const int tx = tid & 15, ty = tid >> 4;
  const int row0 = blockIdx.y * 64, col0 = blockIdx.x * 64;
  float acc[4][4] = {{0.f}};
  const float* Af = (const float*)Ap;
  const bf16* Ab = (const bf16*)Ap;
  const int r = tid >> 2;
  const int kb = (tid & 3) * 4;
  for (int k0 = 0; k0 < K; k0 += 16) {
#pragma unroll
    for (int i = 0; i < 4; ++i) {
      int kk = kb + i, kg = k0 + kk;
      float a = 0.f, w = 0.f;
      if (kg < K) {
        size_t ai = (size_t)(row0 + r) * lda + kg;
        a = ABF ? __bfloat162float(Ab[ai]) : Af[ai];
        int oc = col0 + r;
        if (oc < OC) w = W[(size_t)oc * K + kg];
      }
      As[kk][r] = a;
      Ws[kk][r] = w;
    }
    __syncthreads();
#pragma unroll
    for (int kk = 0; kk < 16; ++kk) {
      float av[4], bv[4];
#pragma unroll
      for (int i = 0; i < 4; ++i) av[i] = As[kk][ty * 4 + i];
#pragma unroll
      for (int j = 0; j < 4; ++j) bv[j] = Ws[kk][tx * 4 + j];
#pragma unroll
      for (int i = 0; i < 4; ++i)
#pragma unroll
        for (int j = 0; j < 4; ++j) acc[i][j] = fmaf(av[i], bv[j], acc[i][j]);
    }
    __syncthreads();
  }
#pragma unroll
  for (int i = 0; i < 4; ++i) {
    int row = row0 + ty * 4 + i;
#pragma unroll
    for (int j = 0; j < 4; ++j) {
      int c = col0 + tx * 4 + j;
      if (c >= OC) continue;
      float v = acc[i][j];
      if (BIAS) v += bias[c];
      if (EYE) { if ((c / 6) == (c % 6)) v += 1.0f; }
      if (GELUE) v = gelu_f(v);
      size_t oi = (size_t)row * OC + c;
      if (OBF) ((bf16*)Cp)[oi] = __float2bfloat16(v);
      else ((float*)Cp)[oi] = v;
    }
  }
}

// ---------------- MFMA GEMM: C = epi(A_bf16 @ W^T), K%64==0, M%BM==0, OC%BN==0 ----------
// W is f32 [OC x K] if WF32 (converted in stage), else bf16.
// LDS layout: per-row 8 chunks of 16B, chunk index XOR-swizzled with (row&7)  [T2]
template<int BM, int BN, bool WF32, bool BIAS, bool GELUE, bool RES, bool OBF>
__global__ __launch_bounds__(256) void mfma_gemm(
    const bf16* __restrict__ A, const void* __restrict__ Wp,
    const float* __restrict__ bias, const float* __restrict__ res,
    void* __restrict__ Cp, int K, int OC) {
  constexpr int MR = BM / 32;   // 16-row frags per wave (2x2 wave grid)
  constexpr int NR = BN / 32;
  __shared__ __align__(16) bf16 As[BM * 64];
  __shared__ __align__(16) bf16 Ws[BN * 64];
  const int tid = threadIdx.x;
  const int wid = tid >> 6, lane = tid & 63;
  const int wm = wid >> 1, wn = wid & 1;
  const int l15 = lane & 15, l4 = lane >> 4;
  const int row0 = blockIdx.y * BM, col0 = blockIdx.x * BN;
  const float* Wf = (const float*)Wp;
  const bf16* Wb = (const bf16*)Wp;
  f32x4 acc[MR][NR];
#pragma unroll
  for (int m = 0; m < MR; ++m)
#pragma unroll
    for (int n = 0; n < NR; ++n) acc[m][n] = (f32x4){0.f, 0.f, 0.f, 0.f};

  for (int k0 = 0; k0 < K; k0 += 64) {
    // ---- stage A tile [BM x 64] ----
#pragma unroll
    for (int t = tid; t < BM * 8; t += 256) {
      int r = t >> 3, c = t & 7;
      uint4 v = *(const uint4*)(A + (size_t)(row0 + r) * K + k0 + c * 8);
      *(uint4*)(As + r * 64 + ((c ^ (r & 7)) * 8)) = v;
    }
    // ---- stage W tile [BN x 64] ----
#pragma unroll
    for (int t = tid; t < BN * 8; t += 256) {
      int r = t >> 3, c = t & 7;
      uint4 v;
      if (WF32) {
        const float* src = Wf + (size_t)(col0 + r) * K + k0 + c * 8;
        float4 f0 = *(const float4*)src;
        float4 f1 = *(const float4*)(src + 4);
        bf16 tmp[8];
        tmp[0] = __float2bfloat16(f0.x); tmp[1] = __float2bfloat16(f0.y);
        tmp[2] = __float2bfloat16(f0.z); tmp[3] = __float2bfloat16(f0.w);
        tmp[4] = __float2bfloat16(f1.x); tmp[5] = __float2bfloat16(f1.y);
        tmp[6] = __float2bfloat16(f1.z); tmp[7] = __float2bfloat16(f1.w);
        v = *(uint4*)tmp;
      } else {
        v = *(const uint4*)(Wb + (size_t)(col0 + r) * K + k0 + c * 8);
      }
      *(uint4*)(Ws + r * 64 + ((c ^ (r & 7)) * 8)) = v;
    }
    __syncthreads();
    // ---- 2 K-steps of 32 ----
#pragma unroll
    for (int kk = 0; kk < 2; ++kk) {
      const int chunk = kk * 4 + l4;
      bfrag a[MR], b[NR];
#pragma unroll
      for (int m = 0; m < MR; ++m) {
        int R = wm * (BM / 2) + m * 16 + l15;
        a[m] = *(const bfrag*)(As + R * 64 + ((chunk ^ (R & 7)) * 8));
      }
#pragma unroll
      for (int n = 0; n < NR; ++n) {
        int R = wn * (BN / 2) + n * 16 + l15;
        b[n] = *(const bfrag*)(Ws + R * 64 + ((chunk ^ (R & 7)) * 8));
      }
#pragma unroll
      for (int m = 0; m < MR; ++m)
#pragma unroll
        for (int n = 0; n < NR; ++n)
          acc[m][n] = __builtin_amdgcn_mfma_f32_16x16x32_bf16(a[m], b[n], acc[m][n], 0, 0, 0);
    }
    __syncthreads();
  }
  // ---- epilogue: C[row=(l>>4)*4+j][col=l&15] per frag ----
#pragma unroll
  for (int m = 0; m < MR; ++m) {
    int rbase = row0 + wm * (BM / 2) + m * 16 + l4 * 4;
#pragma unroll
    for (int n = 0; n < NR; ++n) {
      int c = col0 + wn * (BN / 2) + n * 16 + l15;
      float bs = BIAS ? bias[c] : 0.f;
#pragma unroll
      for (int j = 0; j < 4; ++j) {
        int row = rbase + j;
        float v = acc[m][n][j] + bs;
        if (GELUE) v = gelu_f(v);
        if (RES) v += res[(size_t)row * OC + c];
        size_t oi = (size_t)row * OC + c;
        if (OBF) ((bf16*)Cp)[oi] = __float2bfloat16(v);
        else ((float*)Cp)[oi] = v;
      }
    }
  }
}

// ---------------- BatchNorm stats (sum / sumsq per channel) ----------------
__global__ __launch_bounds__(256) void bn_stats_kernel(const bf16* __restrict__ Y,
                                                       float* __restrict__ stats, int C) {
  const int r0 = blockIdx.x * 256;
  const int tid = threadIdx.x;
  for (int c = tid; c < C; c += 256) {
    float s = 0.f, q = 0.f;
    for (int r = 0; r < 256; ++r) {
      float y = __bfloat162float(Y[(size_t)(r0 + r) * C + c]);
      s += y; q += y * y;
    }
    atomicAdd(&stats[c], s);
    atomicAdd(&stats[C + c], q);
  }
}

__global__ void bn_fin_kernel(const float* __restrict__ stats, const float* __restrict__ g,
                              const float* __restrict__ b, float* __restrict__ ss, int C) {
  int c = blockIdx.x * blockDim.x + threadIdx.x;
  if (c >= C) return;
  const float inv_n = 1.0f / (float)ROWS;
  float m = stats[c] * inv_n;
  float v = stats[C + c] * inv_n - m * m;
  float sc = g[c] * (1.0f / sqrtf(v + 1e-5f));
  ss[c] = sc;
  ss[C + c] = b[c] - m * sc;
}

// ---------------- in-place BN+ReLU on bf16 buffer, 8 elems/thread ----------------
__global__ __launch_bounds__(256) void bnrelu_kernel(bf16* __restrict__ Y,
                                                     const float* __restrict__ ss,
                                                     int C, int total8) {
  for (int i = blockIdx.x * blockDim.x + threadIdx.x; i < total8; i += gridDim.x * blockDim.x) {
    size_t base = (size_t)i * 8;
    int c0 = (int)(base % (size_t)C);
    uint4 v = *(uint4*)(Y + base);
    bf16* e = (bf16*)&v;
#pragma unroll
    for (int j = 0; j < 8; ++j) {
      float f = fmaf(__bfloat162float(e[j]), ss[c0 + j], ss[C + c0 + j]);
      e[j] = __float2bfloat16(fmaxf(f, 0.f));
    }
    *(uint4*)(Y + base) = v;
  }
}

// ---------------- max over M=32 neighbors, BN(+ReLU) applied; f32 or bf16 out --------
template<bool RELU, bool OBF>
__global__ void maxpool_kernel(const bf16* __restrict__ Y, const float* __restrict__ ss,
                               void* __restrict__ out, int C) {
  int gid = blockIdx.x * blockDim.x + threadIdx.x;
  if (gid >= BG * C) return;
  int bg = gid / C, c = gid - bg * C;
  float sc = ss[c], sh = ss[C + c];
  float m = -3.0e38f;
  for (int j = 0; j < M_; ++j) {
    float y = __bfloat162float(Y[((size_t)bg * M_ + j) * C + c]);
    float v = fmaf(y, sc, sh);
    if (RELU) v = fmaxf(v, 0.f);
    m = fmaxf(m, v);
  }
  if (OBF) ((bf16*)out)[gid] = __float2bfloat16(m);
  else ((float*)out)[gid] = m;
}

// ---------------- apply per-group 6x6 TNet transform ----------------
__global__ void tnet_apply_kernel(const float* __restrict__ pg, const float* __restrict__ tmat,
                                  float* __restrict__ pg2) {
  int row = blockIdx.x * blockDim.x + threadIdx.x;
  if (row >= ROWS) return;
  int bg = row >> 5;
  const float* t = tmat + (size_t)bg * 36;
  const float* in = pg + (size_t)row * ATTR_;
  float* o = pg2 + (size_t)row * ATTR_;
  float x[6];
#pragma unroll
  for (int c = 0; c < 6; ++c) x[c] = in[c];
#pragma unroll
  for (int k = 0; k < 6; ++k) {
    float s = 0.f;
#pragma unroll
    for (int c = 0; c < 6; ++c) s = fmaf(x[c], t[c * 6 + k], s);
    o[k] = s;
  }
#pragma unroll
  for (int a = 6; a < ATTR_; ++a) o[a] = in[a];
}

// ---------------- LayerNorm (optionally x+pos, writing h_in); y out bf16 -------------
template<bool ADDPOS>
__global__ __launch_bounds__(128) void ln_kernel(const float* __restrict__ x,
                                                 const float* __restrict__ pos,
                                                 const float* __restrict__ g,
                                                 const float* __restrict__ b,
                                                 float* __restrict__ hin,
                                                 bf16* __restrict__ y) {
  const int row = blockIdx.x;
  const int tid = threadIdx.x;
  float v[3];
  float s = 0.f;
#pragma unroll
  for (int i = 0; i < 3; ++i) {
    int c = tid + i * 128;
    float t = x[(size_t)row * DIM_ + c];
    if (ADDPOS) t += pos[(size_t)row * DIM_ + c];
    v[i] = t; s += t;
  }
  for (int off = 32; off > 0; off >>= 1) s += __shfl_down(s, off);
  __shared__ float sa[2], sb[2];
  if ((tid & 63) == 0) sa[tid >> 6] = s;
  __syncthreads();
  float mean = (sa[0] + sa[1]) * (1.0f / DIM_);
  float q = 0.f;
#pragma unroll
  for (int i = 0; i < 3; ++i) { float d = v[i] - mean; q += d * d; }
  for (int off = 32; off > 0; off >>= 1) q += __shfl_down(q, off);
  if ((tid & 63) == 0) sb[tid >> 6] = q;
  __syncthreads();
  float var = (sb[0] + sb[1]) * (1.0f / DIM_);
  float rs = 1.0f / sqrtf(var + 1e-5f);
#pragma unroll
  for (int i = 0; i < 3; ++i) {
    int c = tid + i * 128;
    if (ADDPOS) hin[(size_t)row * DIM_ + c] = v[i];
    y[(size_t)row * DIM_ + c] = __float2bfloat16(fmaf((v[i] - mean) * rs, g[c], b[c]));
  }
}

// ---------------- attention: one block per (b, h, 64-query tile); bf16 O out ---------
__global__ __launch_bounds__(256) void attn_kernel(const float* __restrict__ qkv,
                                                   bf16* __restrict__ obuf) {
  const int blk = blockIdx.x;
  const int qt = blk & 3;
  const int bh = blk >> 2;
  const int b = bh / HEADS_, h = bh % HEADS_;
  const int tid = threadIdx.x;
  __shared__ float Qs[64][65];
  __shared__ float KVs[256][65];
  __shared__ float Ss[64][257];
  const int n0 = qt * 64;
  const size_t qbase = (size_t)b * G_ * (3 * DIM_);
#pragma unroll 4
  for (int i = 0; i < 16; ++i) {
    int idx = i * 256 + tid;
    int qr = idx >> 6, d = idx & 63;
    Qs[qr][d] = qkv[qbase + (size_t)(n0 + qr) * (3 * DIM_) + h * 64 + d];
  }
#pragma unroll 4
  for (int i = 0; i < 64; ++i) {
    int idx = i * 256 + tid;
    int kr = idx >> 6, d = idx & 63;
    KVs[kr][d] = qkv[qbase + (size_t)kr * (3 * DIM_) + DIM_ + h * 64 + d];
  }
  __syncthreads();
  const int q = tid >> 2, kl = tid & 3;
  float lmax = -3.0e38f;
#pragma unroll 4
  for (int kk = 0; kk < 64; ++kk) {
    int k = kl + kk * 4;
    float s = 0.f;
#pragma unroll
    for (int d = 0; d < 64; ++d) s = fmaf(Qs[q][d], KVs[k][d], s);
    s *= 0.125f;
    Ss[q][k] = s;
    lmax = fmaxf(lmax, s);
  }
  lmax = fmaxf(lmax, __shfl_xor(lmax, 1));
  lmax = fmaxf(lmax, __shfl_xor(lmax, 2));
  float lsum = 0.f;
#pragma unroll 4
  for (int kk = 0; kk < 64; ++kk) {
    int k = kl + kk * 4;
    float e = expf(Ss[q][k] - lmax);
    Ss[q][k] = e;
    lsum += e;
  }
  lsum += __shfl_xor(lsum, 1);
  lsum += __shfl_xor(lsum, 2);
#pragma unroll 4
  for (int kk = 0; kk < 64; ++kk) {
    int k = kl + kk * 4;
    Ss[q][k] = Ss[q][k] / lsum;
  }
  __syncthreads();
#pragma unroll 4
  for (int i = 0; i < 64; ++i) {
    int idx = i * 256 + tid;
    int kr = idx >> 6, d = idx & 63;
    KVs[kr][d] = qkv[qbase + (size_t)kr * (3 * DIM_) + 2 * DIM_ + h * 64 + d];
  }
  __syncthreads();
  float oacc[16];
#pragma unroll
  for (int i = 0; i < 16; ++i) oacc[i] = 0.f;
  for (int k = 0; k < 256; ++k) {
    float s = Ss[q][k];
#pragma unroll
    for (int dd = 0; dd < 16; ++dd) oacc[dd] = fmaf(s, KVs[k][kl + dd * 4], oacc[dd]);
  }
  bf16* ob = obuf + (size_t)(b * G_ + n0 + q) * DIM_ + h * 64;
#pragma unroll
  for (int dd = 0; dd < 16; ++dd) ob[kl + dd * 4] = __float2bfloat16(oacc[dd]);
}

// =======================================================================================
extern "C" void kernel_launch(void* const* d_in, const int* in_sizes, int n_in,
                              void* d_out, int out_size, void* d_ws, size_t ws_size,
                              hipStream_t stream) {
  const float* xyz      = (const float*)d_in[0];
  const float* tn_c1_w  = (const float*)d_in[1];
  const float* tn_c1_b  = (const float*)d_in[2];
  const float* tn_bn1_g = (const float*)d_in[3];
  const float* tn_bn1_b = (const float*)d_in[4];
  const float* tn_c2_w  = (const float*)d_in[5];
  const float* tn_c2_b  = (const float*)d_in[6];
  const float* tn_bn2_g = (const float*)d_in[7];
  const float* tn_bn2_b = (const float*)d_in[8];
  const float* tn_fc_w  = (const float*)d_in[9];
  const float* tn_fc_b  = (const float*)d_in[10];
  const float* e_c1_w = (const float*)d_in[11];
  const float* e_c1_b = (const float*)d_in[12];
  const float* e_bn1_g = (const float*)d_in[13];
  const float* e_bn1_b = (const float*)d_in[14];
  const float* e_c2_w = (const float*)d_in[15];
  const float* e_c2_b = (const float*)d_in[16];
  const float* e_bn2_g = (const float*)d_in[17];
  const float* e_bn2_b = (const float*)d_in[18];
  const float* e_c3_w = (const float*)d_in[19];
  const float* e_c3_b = (const float*)d_in[20];
  const float* e_bn3_g = (const float*)d_in[21];
  const float* e_bn3_b = (const float*)d_in[22];
  const float* e_c4_w = (const float*)d_in[23];
  const float* e_c4_b = (const float*)d_in[24];
  const float* e_bn4_g = (const float*)d_in[25];
  const float* e_bn4_b = (const float*)d_in[26];
  const float* reduce_w = (const float*)d_in[27];
  const float* reduce_b = (const float*)d_in[28];
  const float* pos1_w = (const float*)d_in[29];
  const float* pos1_b = (const float*)d_in[30];
  const float* pos2_w = (const float*)d_in[31];
  const float* pos2_b = (const float*)d_in[32];
  const float* ln1_g = (const float*)d_in[33];
  const float* ln1_b = (const float*)d_in[34];
  const float* qkv_w = (const float*)d_in[35];
  const float* proj_w = (const float*)d_in[36];
  const float* proj_b = (const float*)d_in[37];
  const float* ln2_g = (const float*)d_in[38];
  const float* ln2_b = (const float*)d_in[39];
  const float* fc1_w = (const float*)d_in[40];
  const float* fc1_b = (const float*)d_in[41];
  const float* fc2_w = (const float*)d_in[42];
  const float* fc2_b = (const float*)d_in[43];
  (void)in_sizes; (void)n_in; (void)out_size; (void)ws_size;

  char* ws = (char*)d_ws;
  size_t off = 0;
  auto alloc = [&](size_t bytes) -> void* {
    void* p = ws + off;
    off = (off + bytes + 255) & ~(size_t)255;
    return p;
  };

  char* stats_begin = ws + off;
  float* stats_tn1 = (float*)alloc(2 * 64 * 4);
  float* stats_tn2 = (float*)alloc(2 * 512 * 4);
  float* stats_e1 = (float*)alloc(2 * 128 * 4);
  float* stats_e2 = (float*)alloc(2 * 256 * 4);
  float* stats_e3 = (float*)alloc(2 * 512 * 4);
  float* stats_e4 = (float*)alloc(2 * 1024 * 4);
  size_t stats_len = (size_t)((ws + off) - stats_begin);
  float* ss_tn1 = (float*)alloc(2 * 64 * 4);
  float* ss_tn2 = (float*)alloc(2 * 512 * 4);
  float* ss_e1 = (float*)alloc(2 * 128 * 4);
  float* ss_e2 = (float*)alloc(2 * 256 * 4);
  float* ss_e3 = (float*)alloc(2 * 512 * 4);
  float* ss_e4 = (float*)alloc(2 * 1024 * 4);
  int* cidx = (int*)alloc((size_t)BG * 4);
  int* knn = (int*)alloc((size_t)ROWS * 4);
  float* pn2 = (float*)alloc((size_t)B_ * N_ * 4);
  float* center = (float*)alloc((size_t)BG * 3 * 4);
  float* pg = (float*)alloc((size_t)ROWS * ATTR_ * 4);
  float* pg2 = (float*)alloc((size_t)ROWS * ATTR_ * 4);
  float* hmax = (float*)alloc((size_t)BG * 512 * 4);
  float* tmat = (float*)alloc((size_t)BG * 36 * 4);
  bf16* tokens = (bf16*)alloc((size_t)BG * 1024 * 2);
  float* xb = (float*)alloc((size_t)BG * DIM_ * 4);
  float* posb = (float*)alloc((size_t)BG * DIM_ * 4);
  float* hinb = (float*)alloc((size_t)BG * DIM_ * 4);
  bf16* yb = (bf16*)alloc((size_t)BG * DIM_ * 2);
  float* qkvb = (float*)alloc((size_t)BG * 3 * DIM_ * 4);
  bf16* obf = (bf16*)alloc((size_t)BG * DIM_ * 2);
  bf16* hmlp = (bf16*)alloc((size_t)BG * 1536 * 2);
  float* p1 = (float*)alloc((size_t)BG * 128 * 4);
  bf16* Bbuf0 = (bf16*)alloc((size_t)ROWS * 512 * 2);   // 64 MB
  bf16* Bbuf1 = (bf16*)alloc((size_t)ROWS * 1024 * 2);  // 128 MB

  hipMemsetAsync(stats_begin, 0, stats_len, stream);

  fps_kernel<<<B_, 1024, 0, stream>>>(xyz, cidx);
  pn2_kernel<<<cdiv(B_ * N_, 256), 256, 0, stream>>>(xyz, pn2);
  knn_kernel<<<BG, 256, 0, stream>>>(xyz, pn2, cidx, knn);
  pg_build_kernel<<<cdiv(ROWS, 256), 256, 0, stream>>>(xyz, cidx, knn, pg, center);

  // ---- TNet ----
  gemm_kernel<false, true, false, false, true>
      <<<dim3(1, ROWS / 64), 256, 0, stream>>>(pg, tn_c1_w, tn_c1_b, Bbuf0, ROWS, 6, 64, ATTR_);
  bn_stats_kernel<<<ROWS / 256, 256, 0, stream>>>(Bbuf0, stats_tn1, 64);
  bn_fin_kernel<<<1, 64, 0, stream>>>(stats_tn1, tn_bn1_g, tn_bn1_b, ss_tn1, 64);
  bnrelu_kernel<<<2048, 256, 0, stream>>>(Bbuf0, ss_tn1, 64, ROWS * 64 / 8);
  mfma_gemm<128, 128, true, true, false, false, true>
      <<<dim3(4, ROWS / 128), 256, 0, stream>>>(Bbuf0, tn_c2_w, tn_c2_b, nullptr, Bbuf1, 64, 512);
  bn_stats_kernel<<<ROWS / 256, 256, 0, stream>>>(Bbuf1, stats_tn2, 512);
  bn_fin_kernel<<<2, 256, 0, stream>>>(stats_tn2, tn_bn2_g, tn_bn2_b, ss_tn2, 512);
  maxpool_kernel<true, false><<<cdiv(BG * 512, 256), 256, 0, stream>>>(Bbuf1, ss_tn2, hmax, 512);
  gemm_kernel<false, true, false, true, false>
      <<<dim3(1, BG / 64), 256, 0, stream>>>(hmax, tn_fc_w, tn_fc_b, tmat, BG, 512, 36, 512);
  tnet_apply_kernel<<<cdiv(ROWS, 256), 256, 0, stream>>>(pg, tmat, pg2);

  // ---- Encoder ----
  gemm_kernel<false, true, false, false, true>
      <<<dim3(2, ROWS / 64), 256, 0, stream>>>(pg2, e_c1_w, e_c1_b, Bbuf0, ROWS, ATTR_, 128, ATTR_);
  bn_stats_kernel<<<ROWS / 256, 256, 0, stream>>>(Bbuf0, stats_e1, 128);
  bn_fin_kernel<<<1, 128, 0, stream>>>(stats_e1, e_bn1_g, e_bn1_b, ss_e1, 128);
  bnrelu_kernel<<<2048, 256, 0, stream>>>(Bbuf0, ss_e1, 128, ROWS * 128 / 8);
  mfma_gemm<128, 128, true, true, false, false, true>
      <<<dim3(2, ROWS / 128), 256, 0, stream>>>(Bbuf0, e_c2_w, e_c2_b, nullptr, Bbuf1, 128, 256);
  bn_stats_kernel<<<ROWS / 256, 256, 0, stream>>>(Bbuf1, stats_e2, 256);
  bn_fin_kernel<<<1, 256, 0, stream>>>(stats_e2, e_bn2_g, e_bn2_b, ss_e2, 256);
  bnrelu_kernel<<<2048, 256, 0, stream>>>(Bbuf1, ss_e2, 256, ROWS * 256 / 8);
  mfma_gemm<128, 128, true, true, false, false, true>
      <<<dim3(4, ROWS / 128), 256, 0, stream>>>(Bbuf1, e_c3_w, e_c3_b, nullptr, Bbuf0, 256, 512);
  bn_stats_kernel<<<ROWS / 256, 256, 0, stream>>>(Bbuf0, stats_e3, 512);
  bn_fin_kernel<<<2, 256, 0, stream>>>(stats_e3, e_bn3_g, e_bn3_b, ss_e3, 512);
  bnrelu_kernel<<<2048, 256, 0, stream>>>(Bbuf0, ss_e3, 512, ROWS * 512 / 8);
  mfma_gemm<128, 128, true, true, false, false, true>
      <<<dim3(8, ROWS / 128), 256, 0, stream>>>(Bbuf0, e_c4_w, e_c4_b, nullptr, Bbuf1, 512, 1024);
  bn_stats_kernel<<<ROWS / 256, 256, 0, stream>>>(Bbuf1, stats_e4, 1024);
  bn_fin_kernel<<<4, 256, 0, stream>>>(stats_e4, e_bn4_g, e_bn4_b, ss_e4, 1024);
  maxpool_kernel<false, true><<<cdiv(BG * 1024, 256), 256, 0, stream>>>(Bbuf1, ss_e4, tokens, 1024);

  // ---- reduce + pos ----
  mfma_gemm<64, 64, true, true, false, false, false>
      <<<dim3(6, BG / 64), 256, 0, stream>>>(tokens, reduce_w, reduce_b, nullptr, xb, 1024, DIM_);
  gemm_kernel<false, true, true, false, false>
      <<<dim3(2, BG / 64), 256, 0, stream>>>(center, pos1_w, pos1_b, p1, BG, 3, 128, 3);
  gemm_kernel<false, true, false, false, false>
      <<<dim3(6, BG / 64), 256, 0, stream>>>(p1, pos2_w, pos2_b, posb, BG, 128, DIM_, 128);

  // ---- transformer ----
  int slot = 0;
  for (int i = 0; i < 12; ++i) {
    ln_kernel<true><<<BG, 128, 0, stream>>>(xb, posb, ln1_g + (size_t)i * DIM_,
                                            ln1_b + (size_t)i * DIM_, hinb, yb);
    mfma_gemm<64, 128, true, false, false, false, false>
        <<<dim3(9, BG / 64), 256, 0, stream>>>(yb, qkv_w + (size_t)i * 3 * DIM_ * DIM_,
                                               nullptr, nullptr, qkvb, DIM_, 3 * DIM_);
    attn_kernel<<<B_ * HEADS_ * 4, 256, 0, stream>>>(qkvb, obf);
    mfma_gemm<64, 64, true, true, false, true, false>
        <<<dim3(6, BG / 64), 256, 0, stream>>>(obf, proj_w + (size_t)i * DIM_ * DIM_,
                                               proj_b + (size_t)i * DIM_, hinb, xb, DIM_, DIM_);
    ln_kernel<false><<<BG, 128, 0, stream>>>(xb, nullptr, ln2_g + (size_t)i * DIM_,
                                             ln2_b + (size_t)i * DIM_, nullptr, yb);
    mfma_gemm<64, 128, true, true, true, false, true>
        <<<dim3(12, BG / 64), 256, 0, stream>>>(yb, fc1_w + (size_t)i * 1536 * DIM_,
                                                fc1_b + (size_t)i * 1536, nullptr, hmlp,
                                                DIM_, 1536);
    mfma_gemm<64, 64, true, true, false, true, false>
        <<<dim3(6, BG / 64), 256, 0, stream>>>(hmlp, fc2_w + (size_t)i * DIM_ * 1536,
                                               fc2_b + (size_t)i * DIM_, xb, xb, 1536, DIM_);
    if (i == 3 || i == 7 || i == 11) {
      hipMemcpyAsync((float*)d_out + (size_t)slot * BG * DIM_, xb,
                     (size_t)BG * DIM_ * 4, hipMemcpyDeviceToDevice, stream);
      ++slot;
    }
  }
}